// Round 18
// baseline (324.676 us; speedup 1.0000x reference)
//
#include <hip/hip_runtime.h>
#include <hip/hip_bf16.h>

typedef __hip_bfloat16 bf16;
typedef __attribute__((ext_vector_type(8))) short short8;
typedef __attribute__((ext_vector_type(4))) float f32x4;

#define B_ 8
#define S_ 1024
#define D_ 512
#define H_ 8
#define HD_ 64
#define L_ 128
#define LH_ 16

__device__ __forceinline__ float bfu2f(unsigned short u) {
  unsigned int x = ((unsigned int)u) << 16;
  float f;
  __builtin_memcpy(&f, &x, 4);
  return f;
}
__device__ __forceinline__ unsigned short bfbits(float f) {
  bf16 h = __float2bfloat16(f);
  unsigned short u;
  __builtin_memcpy(&u, &h, 2);
  return u;
}
__device__ __forceinline__ f32x4 mfma_bf16(short8 a, short8 b, f32x4 c) {
  return __builtin_amdgcn_mfma_f32_16x16x32_bf16(a, b, c, 0, 0, 0);
}

// BISECTION LEDGER:
//   GREEN lineage: r8 (374) -> r15 repro -> r16 (+MFMA projections, 325) ->
//   r17 (wide k_qk3w, 319.7). FROZEN: k_pv_mfma, gemm_mfma_out, gemm_mfma_t,
//   prep kernels. VALU-QK family 4/4 green; MFMA-QK family 0/5 red (never).
//   r17 lesson: occupancy was NOT k_qk's limiter (+6us only).
//   r18 (this): k_qk4 = VALU family + float4 stores (16B/lane) via
//   4-consecutive-keys-per-lane + k-major LDS (stride 1028: rows 16B-aligned,
//   write conflicts 2-way=free, reads contiguous). FALLBACK: r17 verbatim.
//   QUARANTINED: AF32-tile-staging MFMA gemm, conditional fragment loads,
//   fused QK+PV, quarter-panel k_qk_mf staging, runtime-lda gemm_mfma_bf.

// ---------------- generic tiled f32 GEMM (GREEN since r5; used for Wcomb) ----
template<bool BT, bool BIAS, bool ABF16, bool CBF16>
__global__ __launch_bounds__(256) void gemm(const void* __restrict__ Ap, int lda,
                                            const void* __restrict__ Bp, int ldb,
                                            void* __restrict__ Cp, int ldc,
                                            const float* __restrict__ bias, int K) {
  __shared__ float As[16][65];
  __shared__ float Bs[16][65];
  const int tid = threadIdx.x;
  const int m0 = blockIdx.y * 64, n0 = blockIdx.x * 64;
  const int ty = tid >> 4, tx = tid & 15;
  float acc[4][4] = {};
  for (int kt = 0; kt < K; kt += 16) {
    {
      const int m = tid >> 2, kq = (tid & 3) * 4;
      if (ABF16) {
        const bf16* A = (const bf16*)Ap;
        ushort4 u = *reinterpret_cast<const ushort4*>(
            reinterpret_cast<const unsigned short*>(A) + (size_t)(m0 + m) * lda + kt + kq);
        As[kq + 0][m] = bfu2f(u.x);
        As[kq + 1][m] = bfu2f(u.y);
        As[kq + 2][m] = bfu2f(u.z);
        As[kq + 3][m] = bfu2f(u.w);
      } else {
        const float* A = (const float*)Ap;
        float4 v = *reinterpret_cast<const float4*>(A + (size_t)(m0 + m) * lda + kt + kq);
        As[kq + 0][m] = v.x;
        As[kq + 1][m] = v.y;
        As[kq + 2][m] = v.z;
        As[kq + 3][m] = v.w;
      }
    }
    if (BT) {
      const int n = tid >> 2, kq = (tid & 3) * 4;
      const float* Bf = (const float*)Bp;
      float4 v = *reinterpret_cast<const float4*>(Bf + (size_t)(n0 + n) * ldb + kt + kq);
      Bs[kq + 0][n] = v.x;
      Bs[kq + 1][n] = v.y;
      Bs[kq + 2][n] = v.z;
      Bs[kq + 3][n] = v.w;
    } else {
      const int k = tid >> 4, nq = (tid & 15) * 4;
      const float* Bf = (const float*)Bp;
      float4 v = *reinterpret_cast<const float4*>(Bf + (size_t)(kt + k) * ldb + n0 + nq);
      Bs[k][nq + 0] = v.x;
      Bs[k][nq + 1] = v.y;
      Bs[k][nq + 2] = v.z;
      Bs[k][nq + 3] = v.w;
    }
    __syncthreads();
#pragma unroll
    for (int k = 0; k < 16; ++k) {
      float a0 = As[k][ty * 4 + 0], a1 = As[k][ty * 4 + 1];
      float a2 = As[k][ty * 4 + 2], a3 = As[k][ty * 4 + 3];
      float b0 = Bs[k][tx * 4 + 0], b1 = Bs[k][tx * 4 + 1];
      float b2 = Bs[k][tx * 4 + 2], b3 = Bs[k][tx * 4 + 3];
      acc[0][0] += a0 * b0; acc[0][1] += a0 * b1; acc[0][2] += a0 * b2; acc[0][3] += a0 * b3;
      acc[1][0] += a1 * b0; acc[1][1] += a1 * b1; acc[1][2] += a1 * b2; acc[1][3] += a1 * b3;
      acc[2][0] += a2 * b0; acc[2][1] += a2 * b1; acc[2][2] += a2 * b2; acc[2][3] += a2 * b3;
      acc[3][0] += a3 * b0; acc[3][1] += a3 * b1; acc[3][2] += a3 * b2; acc[3][3] += a3 * b3;
    }
    __syncthreads();
  }
#pragma unroll
  for (int i = 0; i < 4; ++i)
#pragma unroll
    for (int j = 0; j < 4; ++j) {
      const size_t row = m0 + ty * 4 + i;
      const int col = n0 + tx * 4 + j;
      float v = acc[i][j];
      if (BIAS) v += bias[col];
      if (CBF16)
        reinterpret_cast<bf16*>(Cp)[row * ldc + col] = __float2bfloat16(v);
      else
        reinterpret_cast<float*>(Cp)[row * ldc + col] = v;
    }
}

// ---------------- f32 -> bf16 convert (vectorized; n % 1024 == 0) ----------
__global__ __launch_bounds__(256) void k_conv(const float* __restrict__ in,
                                              bf16* __restrict__ out, int n) {
  int i = (blockIdx.x * 256 + threadIdx.x) * 4;
  if (i >= n) return;
  float4 v = *reinterpret_cast<const float4*>(in + i);
  ushort4 o = { bfbits(v.x), bfbits(v.y), bfbits(v.z), bfbits(v.w) };
  *reinterpret_cast<ushort4*>(out + i) = o;
}

// ---------------- f32 (RxC) -> bf16 transposed (CxR) ----------------
__global__ __launch_bounds__(256) void k_tr_f32_bf16(const float* __restrict__ in,
                                                     bf16* __restrict__ out,
                                                     int R, int C) {
  __shared__ float t[32][33];
  int tx = threadIdx.x & 31, ty = threadIdx.x >> 5;
  int r0 = blockIdx.y * 32, c0 = blockIdx.x * 32;
#pragma unroll
  for (int i = 0; i < 32; i += 8)
    t[ty + i][tx] = in[(size_t)(r0 + ty + i) * C + c0 + tx];
  __syncthreads();
#pragma unroll
  for (int i = 0; i < 32; i += 8)
    out[(size_t)(c0 + ty + i) * R + r0 + tx] = __float2bfloat16(t[tx][ty + i]);
}

// ---------------- copy Wckv into cols 128..255 of wcat ----------------
__global__ __launch_bounds__(256) void k_copy_wckv(const float* __restrict__ Wckv,
                                                   float* __restrict__ wcat) {
  int idx = blockIdx.x * 256 + threadIdx.x;   // 0..65535
  int k = idx >> 7, n = idx & 127;
  wcat[k * 256 + 128 + n] = Wckv[k * 128 + n];
}

// -------- bias_c[j] = sum_d bq[d]*Wuk[j][d] for j<128, else 0 --------
__global__ __launch_bounds__(64) void k_biascomb(const float* __restrict__ bq,
                                                 const float* __restrict__ Wuk,
                                                 float* __restrict__ bias_c) {
  int j = blockIdx.x, lane = threadIdx.x;
  if (j >= L_) { if (lane == 0) bias_c[j] = 0.f; return; }
  float s = 0.f;
  for (int d = lane; d < D_; d += 64) s += bq[d] * Wuk[j * D_ + d];
#pragma unroll
  for (int off = 32; off > 0; off >>= 1) s += __shfl_down(s, off);
  if (lane == 0) bias_c[j] = s;
}

// ---- bf16 MFMA GEMM, compile-time dims (GREEN r16) ----
template<int LDA, int LDB, int LDC, int KK, bool CBF16, bool BIAS>
__global__ __launch_bounds__(256) void gemm_mfma_t(const bf16* __restrict__ Ab,
                                                   const bf16* __restrict__ Bt,
                                                   void* __restrict__ Cp,
                                                   const float* __restrict__ bias) {
  __shared__ __align__(16) short sA[128 * 40];
  __shared__ __align__(16) short sB[128 * 40];
  const int tid = threadIdx.x, lane = tid & 63;
  const int l15 = lane & 15, l4 = lane >> 4;
  const int wm = ((tid >> 6) >> 1) * 64, wn = ((tid >> 6) & 1) * 64;
  const size_t bn0 = (size_t)blockIdx.x * 128, bm0 = (size_t)blockIdx.y * 128;
  const unsigned short* A = reinterpret_cast<const unsigned short*>(Ab);
  const unsigned short* Bu = reinterpret_cast<const unsigned short*>(Bt);
  f32x4 acc[4][4] = {};
  for (int kt = 0; kt < KK; kt += 32) {
    __syncthreads();
#pragma unroll
    for (int i = 0; i < 2; ++i) {
      const int c = tid + i * 256;
      const int row = c >> 2, k8 = (c & 3) * 8;
      *reinterpret_cast<uint4*>(&sA[row * 40 + k8]) =
          *reinterpret_cast<const uint4*>(A + (bm0 + row) * LDA + kt + k8);
      *reinterpret_cast<uint4*>(&sB[row * 40 + k8]) =
          *reinterpret_cast<const uint4*>(Bu + (bn0 + row) * LDB + kt + k8);
    }
    __syncthreads();
    short8 av[4], bv[4];
#pragma unroll
    for (int mf = 0; mf < 4; ++mf)
      av[mf] = *reinterpret_cast<const short8*>(&sA[(wm + mf * 16 + l15) * 40 + l4 * 8]);
#pragma unroll
    for (int nf = 0; nf < 4; ++nf)
      bv[nf] = *reinterpret_cast<const short8*>(&sB[(wn + nf * 16 + l15) * 40 + l4 * 8]);
#pragma unroll
    for (int mf = 0; mf < 4; ++mf)
#pragma unroll
      for (int nf = 0; nf < 4; ++nf)
        acc[mf][nf] = mfma_bf16(av[mf], bv[nf], acc[mf][nf]);
  }
#pragma unroll
  for (int mf = 0; mf < 4; ++mf)
#pragma unroll
    for (int nf = 0; nf < 4; ++nf)
#pragma unroll
      for (int j = 0; j < 4; ++j) {
        const size_t row = bm0 + wm + mf * 16 + l4 * 4 + j;
        const int col = bn0 + wn + nf * 16 + l15;
        float v = acc[mf][nf][j];
        if (BIAS) v += bias[col];
        if (CBF16)
          reinterpret_cast<bf16*>(Cp)[row * LDC + col] = __float2bfloat16(v);
        else
          reinterpret_cast<float*>(Cp)[row * LDC + col] = v;
      }
}

// ------- qk + masked softmax, float4-store variant (VALU family) -------
// vs r17 k_qk3w (GREEN): lane owns 4 CONSECUTIVE keys per group (4 groups);
// qk/aw stores are float4 (16B/lane, 1KB/wave/inst). K staged k-major
// Kl[16][1028]: rows 16B-aligned (1028*4B=257*16), staging writes 2-way
// bank conflict (free), compute reads contiguous stride-1 (conflict-free).
// Dot t-order unchanged -> qk bit-identical; softmax lane-partition differs
// (denom +-1ulp relative). Single stage pass, one barrier.
__global__ __launch_bounds__(512) void k_qk4(const float* __restrict__ xw,
                                             const float* __restrict__ maskg,
                                             float* __restrict__ qk_out,
                                             float* __restrict__ aw_out) {
  __shared__ __align__(16) float Kl[16 * 1028];  // 65.8 KB, k-major
  __shared__ __align__(16) float mkl[S_];        // 4 KB
  __shared__ float qls[16 * 16];                 // 1 KB
  const int bh = blockIdx.y, b = bh >> 3, h = bh & 7;
  const int q0 = blockIdx.x * 16;
  const int tid = threadIdx.x, w = tid >> 6, lane = tid & 63;

  for (int i = tid; i < S_; i += 512) mkl[i] = maskg[b * S_ + i];
  if (tid < 64) {
    const int row = tid >> 2, qq = (tid & 3) * 4;
    float4 v = *reinterpret_cast<const float4*>(
        xw + (size_t)(b * S_ + q0 + row) * 256 + h * LH_ + qq);
    qls[row * 16 + qq + 0] = v.x; qls[row * 16 + qq + 1] = v.y;
    qls[row * 16 + qq + 2] = v.z; qls[row * 16 + qq + 3] = v.w;
  }
  // stage all 1024 keys, k-major
#pragma unroll
  for (int i = 0; i < 8; ++i) {
    const int idx = tid + i * 512;               // 0..4095
    const int key = idx >> 2, qq = (idx & 3) * 4;
    float4 v = *reinterpret_cast<const float4*>(
        xw + (size_t)(b * S_ + key) * 256 + 128 + h * LH_ + qq);
    Kl[(qq + 0) * 1028 + key] = v.x;
    Kl[(qq + 1) * 1028 + key] = v.y;
    Kl[(qq + 2) * 1028 + key] = v.z;
    Kl[(qq + 3) * 1028 + key] = v.w;
  }
  __syncthreads();

  const int r0 = w * 2;                          // wave's first row (0..14)
  float qr[2][16], mq[2];
#pragma unroll
  for (int r = 0; r < 2; ++r) {
#pragma unroll
    for (int t = 0; t < 16; ++t) qr[r][t] = qls[(r0 + r) * 16 + t];
    mq[r] = mkl[q0 + r0 + r];
  }
  const size_t obase = (size_t)bh * S_ * S_;
  float l[2][16];

#pragma unroll
  for (int g = 0; g < 4; ++g) {                  // 4 groups of 4 consecutive keys
    const int key = g * 256 + lane * 4;
    float acc[2][4] = {};
#pragma unroll
    for (int t = 0; t < 16; ++t) {
      float4 kv = *reinterpret_cast<const float4*>(&Kl[t * 1028 + key]);
      acc[0][0] += qr[0][t] * kv.x; acc[0][1] += qr[0][t] * kv.y;
      acc[0][2] += qr[0][t] * kv.z; acc[0][3] += qr[0][t] * kv.w;
      acc[1][0] += qr[1][t] * kv.x; acc[1][1] += qr[1][t] * kv.y;
      acc[1][2] += qr[1][t] * kv.z; acc[1][3] += qr[1][t] * kv.w;
    }
    const float4 mkv = *reinterpret_cast<const float4*>(&mkl[key]);
    const float mk4[4] = { mkv.x, mkv.y, mkv.z, mkv.w };
#pragma unroll
    for (int r = 0; r < 2; ++r) {
      float4 qv;
      float* qvp = reinterpret_cast<float*>(&qv);
#pragma unroll
      for (int j = 0; j < 4; ++j) {
        const float d = acc[r][j] * 0.25f;
        qvp[j] = d;
        const float m = fminf(1.f, __fadd_rn(mq[r], mk4[j]));
        l[r][g * 4 + j] = __fadd_rn(d, __fmul_rn(m, -1e9f));
      }
      *reinterpret_cast<float4*>(qk_out + obase + (size_t)(q0 + r0 + r) * S_ + key) = qv;
    }
  }

#pragma unroll
  for (int r = 0; r < 2; ++r) {
    float M = l[r][0];
#pragma unroll
    for (int idx = 1; idx < 16; ++idx) M = fmaxf(M, l[r][idx]);
#pragma unroll
    for (int st = 1; st < 64; st <<= 1) M = fmaxf(M, __shfl_xor(M, st));
    float s = 0.f;
#pragma unroll
    for (int idx = 0; idx < 16; ++idx) {
      const float e = __expf(l[r][idx] - M);
      l[r][idx] = e;
      s += e;
    }
#pragma unroll
    for (int st = 1; st < 64; st <<= 1) s += __shfl_xor(s, st);
    const float inv = 1.f / s;
    const size_t orow = obase + (size_t)(q0 + r0 + r) * S_;
#pragma unroll
    for (int g = 0; g < 4; ++g) {
      float4 o = { l[r][g * 4 + 0] * inv, l[r][g * 4 + 1] * inv,
                   l[r][g * 4 + 2] * inv, l[r][g * 4 + 3] * inv };
      *reinterpret_cast<float4*>(aw_out + orow + g * 256 + lane * 4) = o;
    }
  }
}

// ---------------- PV via MFMA (FROZEN GREEN r8/r11/r15/r16/r17) --------------
__global__ __launch_bounds__(256) void k_pv_mfma(const float* __restrict__ aw,
                                                 const bf16* __restrict__ vt,
                                                 bf16* __restrict__ attn) {
  __shared__ __align__(16) short Pl[128 * 40];   // 10 KB
  __shared__ __align__(16) short Vl[64 * 40];    // 5 KB
  const int bh = blockIdx.y, b = bh >> 3, h = bh & 7;
  const int q0 = blockIdx.x * 128;
  const int tid = threadIdx.x, w = tid >> 6, lane = tid & 63;
  const int l15 = lane & 15, l4 = lane >> 4;
  const float* A = aw + (size_t)bh * S_ * S_;
  const unsigned short* vtp =
      reinterpret_cast<const unsigned short*>(vt) + (size_t)h * 64 * 8192 + b * S_;
  f32x4 acc[2][4] = {};
  for (int kt = 0; kt < 32; ++kt) {
    __syncthreads();                              // prior frag reads done
    {                                             // stage P: 128 rows x 32 k
      const int r = tid >> 1, half = (tid & 1) * 16;
      const float* src = A + (size_t)(q0 + r) * S_ + kt * 32 + half;
      short* dst = &Pl[r * 40 + half];
#pragma unroll
      for (int i = 0; i < 4; ++i) {
        float4 v = *reinterpret_cast<const float4*>(src + i * 4);
        ushort4 o = { bfbits(v.x), bfbits(v.y), bfbits(v.z), bfbits(v.w) };
        *reinterpret_cast<ushort4*>(dst + i * 4) = o;
      }
    }
    if (tid < 64) {                               // stage V^T: 64 d x 32 k
      const unsigned short* src = vtp + (size_t)tid * 8192 + kt * 32;
      *reinterpret_cast<uint4*>(&Vl[tid * 40 + 0])  = *reinterpret_cast<const uint4*>(src + 0);
      *reinterpret_cast<uint4*>(&Vl[tid * 40 + 8])  = *reinterpret_cast<const uint4*>(src + 8);
      *reinterpret_cast<uint4*>(&Vl[tid * 40 + 16]) = *reinterpret_cast<const uint4*>(src + 16);
      *reinterpret_cast<uint4*>(&Vl[tid * 40 + 24]) = *reinterpret_cast<const uint4*>(src + 24);
    }
    __syncthreads();
    short8 av[2], bv[4];
#pragma unroll
    for (int mf = 0; mf < 2; ++mf)
      av[mf] = *reinterpret_cast<const short8*>(&Pl[(w * 32 + mf * 16 + l15) * 40 + l4 * 8]);
#pragma unroll
    for (int nf = 0; nf < 4; ++nf)
      bv[nf] = *reinterpret_cast<const short8*>(&Vl[(nf * 16 + l15) * 40 + l4 * 8]);
#pragma unroll
    for (int mf = 0; mf < 2; ++mf)
#pragma unroll
      for (int nf = 0; nf < 4; ++nf)
        acc[mf][nf] = mfma_bf16(av[mf], bv[nf], acc[mf][nf]);
  }
#pragma unroll
  for (int mf = 0; mf < 2; ++mf)
#pragma unroll
    for (int nf = 0; nf < 4; ++nf)
#pragma unroll
      for (int j = 0; j < 4; ++j)
        attn[(size_t)(b * S_ + q0 + w * 32 + mf * 16 + l4 * 4 + j) * 512 +
             h * 64 + nf * 16 + l15] = __float2bfloat16(acc[mf][nf][j]);
}

// ------- out = attn_bf @ woT^T + bo via MFMA (FROZEN GREEN) -------
__global__ __launch_bounds__(256) void gemm_mfma_out(const bf16* __restrict__ Ab,
                                                     const bf16* __restrict__ Bt,
                                                     float* __restrict__ C,
                                                     const float* __restrict__ bias) {
  __shared__ __align__(16) short sA[128 * 40];   // 10 KB
  __shared__ __align__(16) short sB[128 * 40];   // 10 KB
  const int tid = threadIdx.x, lane = tid & 63;
  const int l15 = lane & 15, l4 = lane >> 4;
  const int wm = ((tid >> 6) >> 1) * 64, wn = ((tid >> 6) & 1) * 64;
  const size_t bn0 = (size_t)blockIdx.x * 128, bm0 = (size_t)blockIdx.y * 128;
  const unsigned short* A = reinterpret_cast<const unsigned short*>(Ab);
  const unsigned short* Bu = reinterpret_cast<const unsigned short*>(Bt);
  f32x4 acc[4][4] = {};
  for (int kt = 0; kt < 512; kt += 32) {
    __syncthreads();
#pragma unroll
    for (int i = 0; i < 2; ++i) {
      const int c = tid + i * 256;
      const int row = c >> 2, k8 = (c & 3) * 8;
      *reinterpret_cast<uint4*>(&sA[row * 40 + k8]) =
          *reinterpret_cast<const uint4*>(A + (bm0 + row) * 512 + kt + k8);
      *reinterpret_cast<uint4*>(&sB[row * 40 + k8]) =
          *reinterpret_cast<const uint4*>(Bu + (bn0 + row) * 512 + kt + k8);
    }
    __syncthreads();
    short8 av[4], bv[4];
#pragma unroll
    for (int mf = 0; mf < 4; ++mf)
      av[mf] = *reinterpret_cast<const short8*>(&sA[(wm + mf * 16 + l15) * 40 + l4 * 8]);
#pragma unroll
    for (int nf = 0; nf < 4; ++nf)
      bv[nf] = *reinterpret_cast<const short8*>(&sB[(wn + nf * 16 + l15) * 40 + l4 * 8]);
#pragma unroll
    for (int mf = 0; mf < 4; ++mf)
#pragma unroll
      for (int nf = 0; nf < 4; ++nf)
        acc[mf][nf] = mfma_bf16(av[mf], bv[nf], acc[mf][nf]);
  }
#pragma unroll
  for (int mf = 0; mf < 4; ++mf)
#pragma unroll
    for (int nf = 0; nf < 4; ++nf)
#pragma unroll
      for (int j = 0; j < 4; ++j) {
        const size_t row = bm0 + wm + mf * 16 + l4 * 4 + j;
        const int col = bn0 + wn + nf * 16 + l15;
        C[row * 512 + col] = acc[mf][nf][j] + bias[col];
      }
}

extern "C" void kernel_launch(void* const* d_in, const int* in_sizes, int n_in,
                              void* d_out, int out_size, void* d_ws, size_t ws_size,
                              hipStream_t stream) {
  const float* x    = (const float*)d_in[0];
  const float* mask = (const float*)d_in[1];
  const float* Wq   = (const float*)d_in[2];
  const float* bq   = (const float*)d_in[3];
  const float* Wckv = (const float*)d_in[4];
  const float* Wuk  = (const float*)d_in[5];
  const float* Wuv  = (const float*)d_in[6];
  const float* Wo   = (const float*)d_in[7];
  const float* bo   = (const float*)d_in[8];

  float* out    = (float*)d_out;                          // (B,S,D)
  float* aw_out = out + (size_t)B_ * S_ * D_;             // (B,H,S,S)
  float* qk_out = aw_out + (size_t)B_ * H_ * S_ * S_;     // (B,H,S,S)

  // workspace ~29.6 MB (r1 proved 37.5 MB safe); attn_bf aliases xw (disjoint)
  uint8_t* p = (uint8_t*)d_ws;
  auto alloc = [&](size_t bytes) {
    void* r = p;
    p += (bytes + 255) & ~(size_t)255;
    return r;
  };
  float* wcat    = (float*)alloc((size_t)512 * 256 * 4);    // 512 KB [Wcomb|Wckv]
  float* bias_c  = (float*)alloc(256 * 4);
  bf16*  wcatT   = (bf16*)alloc((size_t)256 * 512 * 2);     // 256 KB
  bf16*  wuvT_bf = (bf16*)alloc((size_t)512 * 128 * 2);     // 128 KB
  bf16*  woT     = (bf16*)alloc((size_t)512 * 512 * 2);     // 512 KB
  bf16*  x_bf    = (bf16*)alloc((size_t)8192 * 512 * 2);    // 8 MB
  float* xw      = (float*)alloc((size_t)8192 * 256 * 4);   // 8 MB [q_lat|k_lat]
  bf16*  xw_bf   = (bf16*)alloc((size_t)8192 * 256 * 2);    // 4 MB
  bf16*  vt      = (bf16*)alloc((size_t)512 * 8192 * 2);    // 8 MB V^T
  bf16*  attn_bf = (bf16*)xw;                               // alias, 8 MB

  // Wcomb (cols 0..127 of wcat) = Wq @ Wuk^T  (green f32 gemm)
  gemm<true, false, false, false><<<dim3(2, 8), 256, 0, stream>>>(
      Wq, 512, Wuk, 512, wcat, 256, nullptr, 512);
  // Wckv -> cols 128..255 of wcat
  k_copy_wckv<<<256, 256, 0, stream>>>(Wckv, wcat);
  k_biascomb<<<256, 64, 0, stream>>>(bq, Wuk, bias_c);
  // wcatT(256x512 bf16) = wcat^T
  k_tr_f32_bf16<<<dim3(8, 16), 256, 0, stream>>>(wcat, wcatT, 512, 256);
  k_tr_f32_bf16<<<dim3(16, 4), 256, 0, stream>>>(Wuv, wuvT_bf, 128, 512);
  k_tr_f32_bf16<<<dim3(16, 16), 256, 0, stream>>>(Wo, woT, 512, 512);
  // x_bf = bf16(x)
  k_conv<<<4096, 256, 0, stream>>>(x, x_bf, 8192 * 512);
  // xw(f32) = x_bf @ wcatT^T + [bias_c|0]   (MFMA, compile-time dims)
  gemm_mfma_t<512, 512, 256, 512, false, true><<<dim3(2, 64), 256, 0, stream>>>(
      x_bf, wcatT, xw, bias_c);
  // xw_bf = bf16(xw)  (k_lat operand for vt)
  k_conv<<<2048, 256, 0, stream>>>(xw, xw_bf, 8192 * 256);
  // vt(512x8192 bf16) = wuvT_bf @ k_lat^T   (MFMA, compile-time dims)
  gemm_mfma_t<128, 256, 8192, 128, true, false><<<dim3(64, 4), 256, 0, stream>>>(
      wuvT_bf, xw_bf + 128, vt, nullptr);
  // qk_values + attn_weights  (VALU family, float4 stores)
  k_qk4<<<dim3(64, 64), 512, 0, stream>>>(xw, mask, qk_out, aw_out);
  // attn = aw @ V  (FROZEN; writes over xw — dead)
  k_pv_mfma<<<dim3(8, 64), 256, 0, stream>>>(aw_out, vt, attn_bf);
  // out = attn @ Wo + bo  (FROZEN)
  gemm_mfma_out<<<dim3(4, 64), 256, 0, stream>>>(attn_bf, woT, out, bo);
  (void)in_sizes; (void)n_in; (void)out_size; (void)ws_size;
}

// Round 19
// 318.185 us; speedup vs baseline: 1.0204x; 1.0204x over previous
//
#include <hip/hip_runtime.h>
#include <hip/hip_bf16.h>

typedef __hip_bfloat16 bf16;
typedef __attribute__((ext_vector_type(8))) short short8;
typedef __attribute__((ext_vector_type(4))) float f32x4;

#define B_ 8
#define S_ 1024
#define D_ 512
#define H_ 8
#define HD_ 64
#define L_ 128
#define LH_ 16

__device__ __forceinline__ float bfu2f(unsigned short u) {
  unsigned int x = ((unsigned int)u) << 16;
  float f;
  __builtin_memcpy(&f, &x, 4);
  return f;
}
__device__ __forceinline__ unsigned short bfbits(float f) {
  bf16 h = __float2bfloat16(f);
  unsigned short u;
  __builtin_memcpy(&u, &h, 2);
  return u;
}
__device__ __forceinline__ f32x4 mfma_bf16(short8 a, short8 b, f32x4 c) {
  return __builtin_amdgcn_mfma_f32_16x16x32_bf16(a, b, c, 0, 0, 0);
}

// FINAL CONFIGURATION (= r17, session best: 319.7us, absmax 0.0039).
// BISECTION LEDGER (final):
//   GREEN lineage: r5 all-f32 (1048) -> r6 tiled qk (736) -> r7 reg-logits
//   (564) -> r8 MFMA pv/out (374) -> r15 repro (374) -> r16 MFMA projections
//   (325) -> r17 wide k_qk3w (319.7). r18 float4-store variant: neutral (324.7).
//   FROZEN: k_pv_mfma, gemm_mfma_out, gemm_mfma_t, prep kernels, k_qk3w.
//   QUARANTINED (red, cause never diagnosed beyond empirics): MFMA-QK family
//   (0/5), AF32-tile-staging MFMA gemm, conditional fragment loads, fused
//   QK+PV, quarter-panel k_qk_mf staging, runtime-lda gemm_mfma_bf.
//   Falsified perf theories for k_qk: occupancy (r17 +6us), store width (r18 0).
//   Remaining ~2x-vs-HBM-floor gap requires the quarantined fusion.

// ---------------- generic tiled f32 GEMM (GREEN since r5; used for Wcomb) ----
template<bool BT, bool BIAS, bool ABF16, bool CBF16>
__global__ __launch_bounds__(256) void gemm(const void* __restrict__ Ap, int lda,
                                            const void* __restrict__ Bp, int ldb,
                                            void* __restrict__ Cp, int ldc,
                                            const float* __restrict__ bias, int K) {
  __shared__ float As[16][65];
  __shared__ float Bs[16][65];
  const int tid = threadIdx.x;
  const int m0 = blockIdx.y * 64, n0 = blockIdx.x * 64;
  const int ty = tid >> 4, tx = tid & 15;
  float acc[4][4] = {};
  for (int kt = 0; kt < K; kt += 16) {
    {
      const int m = tid >> 2, kq = (tid & 3) * 4;
      if (ABF16) {
        const bf16* A = (const bf16*)Ap;
        ushort4 u = *reinterpret_cast<const ushort4*>(
            reinterpret_cast<const unsigned short*>(A) + (size_t)(m0 + m) * lda + kt + kq);
        As[kq + 0][m] = bfu2f(u.x);
        As[kq + 1][m] = bfu2f(u.y);
        As[kq + 2][m] = bfu2f(u.z);
        As[kq + 3][m] = bfu2f(u.w);
      } else {
        const float* A = (const float*)Ap;
        float4 v = *reinterpret_cast<const float4*>(A + (size_t)(m0 + m) * lda + kt + kq);
        As[kq + 0][m] = v.x;
        As[kq + 1][m] = v.y;
        As[kq + 2][m] = v.z;
        As[kq + 3][m] = v.w;
      }
    }
    if (BT) {
      const int n = tid >> 2, kq = (tid & 3) * 4;
      const float* Bf = (const float*)Bp;
      float4 v = *reinterpret_cast<const float4*>(Bf + (size_t)(n0 + n) * ldb + kt + kq);
      Bs[kq + 0][n] = v.x;
      Bs[kq + 1][n] = v.y;
      Bs[kq + 2][n] = v.z;
      Bs[kq + 3][n] = v.w;
    } else {
      const int k = tid >> 4, nq = (tid & 15) * 4;
      const float* Bf = (const float*)Bp;
      float4 v = *reinterpret_cast<const float4*>(Bf + (size_t)(kt + k) * ldb + n0 + nq);
      Bs[k][nq + 0] = v.x;
      Bs[k][nq + 1] = v.y;
      Bs[k][nq + 2] = v.z;
      Bs[k][nq + 3] = v.w;
    }
    __syncthreads();
#pragma unroll
    for (int k = 0; k < 16; ++k) {
      float a0 = As[k][ty * 4 + 0], a1 = As[k][ty * 4 + 1];
      float a2 = As[k][ty * 4 + 2], a3 = As[k][ty * 4 + 3];
      float b0 = Bs[k][tx * 4 + 0], b1 = Bs[k][tx * 4 + 1];
      float b2 = Bs[k][tx * 4 + 2], b3 = Bs[k][tx * 4 + 3];
      acc[0][0] += a0 * b0; acc[0][1] += a0 * b1; acc[0][2] += a0 * b2; acc[0][3] += a0 * b3;
      acc[1][0] += a1 * b0; acc[1][1] += a1 * b1; acc[1][2] += a1 * b2; acc[1][3] += a1 * b3;
      acc[2][0] += a2 * b0; acc[2][1] += a2 * b1; acc[2][2] += a2 * b2; acc[2][3] += a2 * b3;
      acc[3][0] += a3 * b0; acc[3][1] += a3 * b1; acc[3][2] += a3 * b2; acc[3][3] += a3 * b3;
    }
    __syncthreads();
  }
#pragma unroll
  for (int i = 0; i < 4; ++i)
#pragma unroll
    for (int j = 0; j < 4; ++j) {
      const size_t row = m0 + ty * 4 + i;
      const int col = n0 + tx * 4 + j;
      float v = acc[i][j];
      if (BIAS) v += bias[col];
      if (CBF16)
        reinterpret_cast<bf16*>(Cp)[row * ldc + col] = __float2bfloat16(v);
      else
        reinterpret_cast<float*>(Cp)[row * ldc + col] = v;
    }
}

// ---------------- f32 -> bf16 convert (vectorized; n % 1024 == 0) ----------
__global__ __launch_bounds__(256) void k_conv(const float* __restrict__ in,
                                              bf16* __restrict__ out, int n) {
  int i = (blockIdx.x * 256 + threadIdx.x) * 4;
  if (i >= n) return;
  float4 v = *reinterpret_cast<const float4*>(in + i);
  ushort4 o = { bfbits(v.x), bfbits(v.y), bfbits(v.z), bfbits(v.w) };
  *reinterpret_cast<ushort4*>(out + i) = o;
}

// ---------------- f32 (RxC) -> bf16 transposed (CxR) ----------------
__global__ __launch_bounds__(256) void k_tr_f32_bf16(const float* __restrict__ in,
                                                     bf16* __restrict__ out,
                                                     int R, int C) {
  __shared__ float t[32][33];
  int tx = threadIdx.x & 31, ty = threadIdx.x >> 5;
  int r0 = blockIdx.y * 32, c0 = blockIdx.x * 32;
#pragma unroll
  for (int i = 0; i < 32; i += 8)
    t[ty + i][tx] = in[(size_t)(r0 + ty + i) * C + c0 + tx];
  __syncthreads();
#pragma unroll
  for (int i = 0; i < 32; i += 8)
    out[(size_t)(c0 + ty + i) * R + r0 + tx] = __float2bfloat16(t[tx][ty + i]);
}

// ---------------- copy Wckv into cols 128..255 of wcat ----------------
__global__ __launch_bounds__(256) void k_copy_wckv(const float* __restrict__ Wckv,
                                                   float* __restrict__ wcat) {
  int idx = blockIdx.x * 256 + threadIdx.x;   // 0..65535
  int k = idx >> 7, n = idx & 127;
  wcat[k * 256 + 128 + n] = Wckv[k * 128 + n];
}

// -------- bias_c[j] = sum_d bq[d]*Wuk[j][d] for j<128, else 0 --------
__global__ __launch_bounds__(64) void k_biascomb(const float* __restrict__ bq,
                                                 const float* __restrict__ Wuk,
                                                 float* __restrict__ bias_c) {
  int j = blockIdx.x, lane = threadIdx.x;
  if (j >= L_) { if (lane == 0) bias_c[j] = 0.f; return; }
  float s = 0.f;
  for (int d = lane; d < D_; d += 64) s += bq[d] * Wuk[j * D_ + d];
#pragma unroll
  for (int off = 32; off > 0; off >>= 1) s += __shfl_down(s, off);
  if (lane == 0) bias_c[j] = s;
}

// ---- bf16 MFMA GEMM, compile-time dims (GREEN r16) ----
template<int LDA, int LDB, int LDC, int KK, bool CBF16, bool BIAS>
__global__ __launch_bounds__(256) void gemm_mfma_t(const bf16* __restrict__ Ab,
                                                   const bf16* __restrict__ Bt,
                                                   void* __restrict__ Cp,
                                                   const float* __restrict__ bias) {
  __shared__ __align__(16) short sA[128 * 40];
  __shared__ __align__(16) short sB[128 * 40];
  const int tid = threadIdx.x, lane = tid & 63;
  const int l15 = lane & 15, l4 = lane >> 4;
  const int wm = ((tid >> 6) >> 1) * 64, wn = ((tid >> 6) & 1) * 64;
  const size_t bn0 = (size_t)blockIdx.x * 128, bm0 = (size_t)blockIdx.y * 128;
  const unsigned short* A = reinterpret_cast<const unsigned short*>(Ab);
  const unsigned short* Bu = reinterpret_cast<const unsigned short*>(Bt);
  f32x4 acc[4][4] = {};
  for (int kt = 0; kt < KK; kt += 32) {
    __syncthreads();
#pragma unroll
    for (int i = 0; i < 2; ++i) {
      const int c = tid + i * 256;
      const int row = c >> 2, k8 = (c & 3) * 8;
      *reinterpret_cast<uint4*>(&sA[row * 40 + k8]) =
          *reinterpret_cast<const uint4*>(A + (bm0 + row) * LDA + kt + k8);
      *reinterpret_cast<uint4*>(&sB[row * 40 + k8]) =
          *reinterpret_cast<const uint4*>(Bu + (bn0 + row) * LDB + kt + k8);
    }
    __syncthreads();
    short8 av[4], bv[4];
#pragma unroll
    for (int mf = 0; mf < 4; ++mf)
      av[mf] = *reinterpret_cast<const short8*>(&sA[(wm + mf * 16 + l15) * 40 + l4 * 8]);
#pragma unroll
    for (int nf = 0; nf < 4; ++nf)
      bv[nf] = *reinterpret_cast<const short8*>(&sB[(wn + nf * 16 + l15) * 40 + l4 * 8]);
#pragma unroll
    for (int mf = 0; mf < 4; ++mf)
#pragma unroll
      for (int nf = 0; nf < 4; ++nf)
        acc[mf][nf] = mfma_bf16(av[mf], bv[nf], acc[mf][nf]);
  }
#pragma unroll
  for (int mf = 0; mf < 4; ++mf)
#pragma unroll
    for (int nf = 0; nf < 4; ++nf)
#pragma unroll
      for (int j = 0; j < 4; ++j) {
        const size_t row = bm0 + wm + mf * 16 + l4 * 4 + j;
        const int col = bn0 + wn + nf * 16 + l15;
        float v = acc[mf][nf][j];
        if (BIAS) v += bias[col];
        if (CBF16)
          reinterpret_cast<bf16*>(Cp)[row * LDC + col] = __float2bfloat16(v);
        else
          reinterpret_cast<float*>(Cp)[row * LDC + col] = v;
      }
}

// ------- tiled qk + masked softmax, WIDE (GREEN r17, session best) ----
__global__ __launch_bounds__(512) void k_qk3w(const float* __restrict__ xw,
                                              const float* __restrict__ maskg,
                                              float* __restrict__ qk_out,
                                              float* __restrict__ aw_out) {
  __shared__ __align__(16) float Kl[512 * 20];   // 40 KB
  __shared__ float mkl[S_];                      // 4 KB
  __shared__ float qls[16 * 16];                 // 1 KB
  const int bh = blockIdx.y, b = bh >> 3, h = bh & 7;
  const int q0 = blockIdx.x * 16;
  const int tid = threadIdx.x, w = tid >> 6, lane = tid & 63;

  for (int i = tid; i < S_; i += 512) mkl[i] = maskg[b * S_ + i];
  if (tid < 64) {
    const int row = tid >> 2, qq = (tid & 3) * 4;
    float4 v = *reinterpret_cast<const float4*>(
        xw + (size_t)(b * S_ + q0 + row) * 256 + h * LH_ + qq);
    qls[row * 16 + qq + 0] = v.x; qls[row * 16 + qq + 1] = v.y;
    qls[row * 16 + qq + 2] = v.z; qls[row * 16 + qq + 3] = v.w;
  }
  __syncthreads();

  const int r0 = w * 2;                          // wave's first row (0..14)
  float qr[2][16], mq[2];
#pragma unroll
  for (int r = 0; r < 2; ++r) {
#pragma unroll
    for (int t = 0; t < 16; ++t) qr[r][t] = qls[(r0 + r) * 16 + t];
    mq[r] = mkl[q0 + r0 + r];
  }
  const size_t obase = (size_t)bh * S_ * S_;
  float l[2][16];

#pragma unroll
  for (int half = 0; half < 2; ++half) {
    if (half) __syncthreads();
#pragma unroll
    for (int i = 0; i < 4; ++i) {                // 512 keys x 16 f32, 512 thr
      const int idx = tid + i * 512;
      const int key = idx >> 2, qq = (idx & 3) * 4;
      float4 v = *reinterpret_cast<const float4*>(
          xw + (size_t)(b * S_ + half * 512 + key) * 256 + 128 + h * LH_ + qq);
      *reinterpret_cast<float4*>(&Kl[key * 20 + qq]) = v;
    }
    __syncthreads();
#pragma unroll
    for (int c = 0; c < 8; ++c) {
      const int lkey = c * 64 + lane;
      const int key = half * 512 + lkey;
      float kv[16];
#pragma unroll
      for (int t = 0; t < 16; t += 4) {
        float4 v = *reinterpret_cast<const float4*>(&Kl[lkey * 20 + t]);
        kv[t] = v.x; kv[t + 1] = v.y; kv[t + 2] = v.z; kv[t + 3] = v.w;
      }
      const float mk = mkl[key];
#pragma unroll
      for (int r = 0; r < 2; ++r) {
        float d = 0.f;
#pragma unroll
        for (int t = 0; t < 16; ++t) d += qr[r][t] * kv[t];
        d *= 0.25f;
        qk_out[obase + (size_t)(q0 + r0 + r) * S_ + key] = d;
        const float m = fminf(1.f, __fadd_rn(mq[r], mk));
        l[r][half * 8 + c] = __fadd_rn(d, __fmul_rn(m, -1e9f));
      }
    }
  }

#pragma unroll
  for (int r = 0; r < 2; ++r) {
    float M = l[r][0];
#pragma unroll
    for (int idx = 1; idx < 16; ++idx) M = fmaxf(M, l[r][idx]);
#pragma unroll
    for (int st = 1; st < 64; st <<= 1) M = fmaxf(M, __shfl_xor(M, st));
    float s = 0.f;
#pragma unroll
    for (int idx = 0; idx < 16; ++idx) {
      const float e = __expf(l[r][idx] - M);
      l[r][idx] = e;
      s += e;
    }
#pragma unroll
    for (int st = 1; st < 64; st <<= 1) s += __shfl_xor(s, st);
    const float inv = 1.f / s;
    const size_t orow = obase + (size_t)(q0 + r0 + r) * S_;
#pragma unroll
    for (int idx = 0; idx < 16; ++idx)
      aw_out[orow + (idx >> 3) * 512 + (idx & 7) * 64 + lane] = l[r][idx] * inv;
  }
}

// ---------------- PV via MFMA (FROZEN GREEN r8/r11/r15/r16/r17) --------------
__global__ __launch_bounds__(256) void k_pv_mfma(const float* __restrict__ aw,
                                                 const bf16* __restrict__ vt,
                                                 bf16* __restrict__ attn) {
  __shared__ __align__(16) short Pl[128 * 40];   // 10 KB
  __shared__ __align__(16) short Vl[64 * 40];    // 5 KB
  const int bh = blockIdx.y, b = bh >> 3, h = bh & 7;
  const int q0 = blockIdx.x * 128;
  const int tid = threadIdx.x, w = tid >> 6, lane = tid & 63;
  const int l15 = lane & 15, l4 = lane >> 4;
  const float* A = aw + (size_t)bh * S_ * S_;
  const unsigned short* vtp =
      reinterpret_cast<const unsigned short*>(vt) + (size_t)h * 64 * 8192 + b * S_;
  f32x4 acc[2][4] = {};
  for (int kt = 0; kt < 32; ++kt) {
    __syncthreads();                              // prior frag reads done
    {                                             // stage P: 128 rows x 32 k
      const int r = tid >> 1, half = (tid & 1) * 16;
      const float* src = A + (size_t)(q0 + r) * S_ + kt * 32 + half;
      short* dst = &Pl[r * 40 + half];
#pragma unroll
      for (int i = 0; i < 4; ++i) {
        float4 v = *reinterpret_cast<const float4*>(src + i * 4);
        ushort4 o = { bfbits(v.x), bfbits(v.y), bfbits(v.z), bfbits(v.w) };
        *reinterpret_cast<ushort4*>(dst + i * 4) = o;
      }
    }
    if (tid < 64) {                               // stage V^T: 64 d x 32 k
      const unsigned short* src = vtp + (size_t)tid * 8192 + kt * 32;
      *reinterpret_cast<uint4*>(&Vl[tid * 40 + 0])  = *reinterpret_cast<const uint4*>(src + 0);
      *reinterpret_cast<uint4*>(&Vl[tid * 40 + 8])  = *reinterpret_cast<const uint4*>(src + 8);
      *reinterpret_cast<uint4*>(&Vl[tid * 40 + 16]) = *reinterpret_cast<const uint4*>(src + 16);
      *reinterpret_cast<uint4*>(&Vl[tid * 40 + 24]) = *reinterpret_cast<const uint4*>(src + 24);
    }
    __syncthreads();
    short8 av[2], bv[4];
#pragma unroll
    for (int mf = 0; mf < 2; ++mf)
      av[mf] = *reinterpret_cast<const short8*>(&Pl[(w * 32 + mf * 16 + l15) * 40 + l4 * 8]);
#pragma unroll
    for (int nf = 0; nf < 4; ++nf)
      bv[nf] = *reinterpret_cast<const short8*>(&Vl[(nf * 16 + l15) * 40 + l4 * 8]);
#pragma unroll
    for (int mf = 0; mf < 2; ++mf)
#pragma unroll
      for (int nf = 0; nf < 4; ++nf)
        acc[mf][nf] = mfma_bf16(av[mf], bv[nf], acc[mf][nf]);
  }
#pragma unroll
  for (int mf = 0; mf < 2; ++mf)
#pragma unroll
    for (int nf = 0; nf < 4; ++nf)
#pragma unroll
      for (int j = 0; j < 4; ++j)
        attn[(size_t)(b * S_ + q0 + w * 32 + mf * 16 + l4 * 4 + j) * 512 +
             h * 64 + nf * 16 + l15] = __float2bfloat16(acc[mf][nf][j]);
}

// ------- out = attn_bf @ woT^T + bo via MFMA (FROZEN GREEN) -------
__global__ __launch_bounds__(256) void gemm_mfma_out(const bf16* __restrict__ Ab,
                                                     const bf16* __restrict__ Bt,
                                                     float* __restrict__ C,
                                                     const float* __restrict__ bias) {
  __shared__ __align__(16) short sA[128 * 40];   // 10 KB
  __shared__ __align__(16) short sB[128 * 40];   // 10 KB
  const int tid = threadIdx.x, lane = tid & 63;
  const int l15 = lane & 15, l4 = lane >> 4;
  const int wm = ((tid >> 6) >> 1) * 64, wn = ((tid >> 6) & 1) * 64;
  const size_t bn0 = (size_t)blockIdx.x * 128, bm0 = (size_t)blockIdx.y * 128;
  const unsigned short* A = reinterpret_cast<const unsigned short*>(Ab);
  const unsigned short* Bu = reinterpret_cast<const unsigned short*>(Bt);
  f32x4 acc[4][4] = {};
  for (int kt = 0; kt < 512; kt += 32) {
    __syncthreads();
#pragma unroll
    for (int i = 0; i < 2; ++i) {
      const int c = tid + i * 256;
      const int row = c >> 2, k8 = (c & 3) * 8;
      *reinterpret_cast<uint4*>(&sA[row * 40 + k8]) =
          *reinterpret_cast<const uint4*>(A + (bm0 + row) * 512 + kt + k8);
      *reinterpret_cast<uint4*>(&sB[row * 40 + k8]) =
          *reinterpret_cast<const uint4*>(Bu + (bn0 + row) * 512 + kt + k8);
    }
    __syncthreads();
    short8 av[4], bv[4];
#pragma unroll
    for (int mf = 0; mf < 4; ++mf)
      av[mf] = *reinterpret_cast<const short8*>(&sA[(wm + mf * 16 + l15) * 40 + l4 * 8]);
#pragma unroll
    for (int nf = 0; nf < 4; ++nf)
      bv[nf] = *reinterpret_cast<const short8*>(&sB[(wn + nf * 16 + l15) * 40 + l4 * 8]);
#pragma unroll
    for (int mf = 0; mf < 4; ++mf)
#pragma unroll
      for (int nf = 0; nf < 4; ++nf)
        acc[mf][nf] = mfma_bf16(av[mf], bv[nf], acc[mf][nf]);
  }
#pragma unroll
  for (int mf = 0; mf < 4; ++mf)
#pragma unroll
    for (int nf = 0; nf < 4; ++nf)
#pragma unroll
      for (int j = 0; j < 4; ++j) {
        const size_t row = bm0 + wm + mf * 16 + l4 * 4 + j;
        const int col = bn0 + wn + nf * 16 + l15;
        C[row * 512 + col] = acc[mf][nf][j] + bias[col];
      }
}

extern "C" void kernel_launch(void* const* d_in, const int* in_sizes, int n_in,
                              void* d_out, int out_size, void* d_ws, size_t ws_size,
                              hipStream_t stream) {
  const float* x    = (const float*)d_in[0];
  const float* mask = (const float*)d_in[1];
  const float* Wq   = (const float*)d_in[2];
  const float* bq   = (const float*)d_in[3];
  const float* Wckv = (const float*)d_in[4];
  const float* Wuk  = (const float*)d_in[5];
  const float* Wuv  = (const float*)d_in[6];
  const float* Wo   = (const float*)d_in[7];
  const float* bo   = (const float*)d_in[8];

  float* out    = (float*)d_out;                          // (B,S,D)
  float* aw_out = out + (size_t)B_ * S_ * D_;             // (B,H,S,S)
  float* qk_out = aw_out + (size_t)B_ * H_ * S_ * S_;     // (B,H,S,S)

  // workspace ~29.6 MB (r1 proved 37.5 MB safe); attn_bf aliases xw (disjoint)
  uint8_t* p = (uint8_t*)d_ws;
  auto alloc = [&](size_t bytes) {
    void* r = p;
    p += (bytes + 255) & ~(size_t)255;
    return r;
  };
  float* wcat    = (float*)alloc((size_t)512 * 256 * 4);    // 512 KB [Wcomb|Wckv]
  float* bias_c  = (float*)alloc(256 * 4);
  bf16*  wcatT   = (bf16*)alloc((size_t)256 * 512 * 2);     // 256 KB
  bf16*  wuvT_bf = (bf16*)alloc((size_t)512 * 128 * 2);     // 128 KB
  bf16*  woT     = (bf16*)alloc((size_t)512 * 512 * 2);     // 512 KB
  bf16*  x_bf    = (bf16*)alloc((size_t)8192 * 512 * 2);    // 8 MB
  float* xw      = (float*)alloc((size_t)8192 * 256 * 4);   // 8 MB [q_lat|k_lat]
  bf16*  xw_bf   = (bf16*)alloc((size_t)8192 * 256 * 2);    // 4 MB
  bf16*  vt      = (bf16*)alloc((size_t)512 * 8192 * 2);    // 8 MB V^T
  bf16*  attn_bf = (bf16*)xw;                               // alias, 8 MB

  // Wcomb (cols 0..127 of wcat) = Wq @ Wuk^T  (green f32 gemm)
  gemm<true, false, false, false><<<dim3(2, 8), 256, 0, stream>>>(
      Wq, 512, Wuk, 512, wcat, 256, nullptr, 512);
  // Wckv -> cols 128..255 of wcat
  k_copy_wckv<<<256, 256, 0, stream>>>(Wckv, wcat);
  k_biascomb<<<256, 64, 0, stream>>>(bq, Wuk, bias_c);
  // wcatT(256x512 bf16) = wcat^T
  k_tr_f32_bf16<<<dim3(8, 16), 256, 0, stream>>>(wcat, wcatT, 512, 256);
  k_tr_f32_bf16<<<dim3(16, 4), 256, 0, stream>>>(Wuv, wuvT_bf, 128, 512);
  k_tr_f32_bf16<<<dim3(16, 16), 256, 0, stream>>>(Wo, woT, 512, 512);
  // x_bf = bf16(x)
  k_conv<<<4096, 256, 0, stream>>>(x, x_bf, 8192 * 512);
  // xw(f32) = x_bf @ wcatT^T + [bias_c|0]   (MFMA, compile-time dims)
  gemm_mfma_t<512, 512, 256, 512, false, true><<<dim3(2, 64), 256, 0, stream>>>(
      x_bf, wcatT, xw, bias_c);
  // xw_bf = bf16(xw)  (k_lat operand for vt)
  k_conv<<<2048, 256, 0, stream>>>(xw, xw_bf, 8192 * 256);
  // vt(512x8192 bf16) = wuvT_bf @ k_lat^T   (MFMA, compile-time dims)
  gemm_mfma_t<128, 256, 8192, 128, true, false><<<dim3(64, 4), 256, 0, stream>>>(
      wuvT_bf, xw_bf + 128, vt, nullptr);
  // qk_values + attn_weights  (VALU family, wide blocks — session best)
  k_qk3w<<<dim3(64, 64), 512, 0, stream>>>(xw, mask, qk_out, aw_out);
  // attn = aw @ V  (FROZEN; writes over xw — dead)
  k_pv_mfma<<<dim3(8, 64), 256, 0, stream>>>(aw_out, vt, attn_bf);
  // out = attn @ Wo + bo  (FROZEN)
  gemm_mfma_out<<<dim3(4, 64), 256, 0, stream>>>(attn_bf, woT, out, bo);
  (void)in_sizes; (void)n_in; (void)out_size; (void)ws_size;
}